// Round 10
// baseline (203.994 us; speedup 1.0000x reference)
//
#include <hip/hip_runtime.h>

// GraphAttention fused forward for MI355X (gfx950).
// MFMA PV; double-buffered LDS staging with loads-after-barrier placement
// (defeats the vmcnt(0)-before-s_barrier drain); 2 i-rows/lane.
// B=4, N=2048, F=64, FP=32, H=4.  Output: [B,N,H*FP] f32 ++ uloss ++ eloss.

#define B_ 4
#define N_ 2048
#define F_ 64
#define FP_ 32
#define H_ 4
#define C_ 128
#define IT_ 32                 // i-rows per attn block (2 per lane)
#define ITILES_ (N_ / IT_)     // 64
#define JCA_ 4                 // j-chunks -> grid 1024 = 4 blocks/CU exactly
#define JSPANA_ (N_ / JCA_)    // 512
#define JST_ 64                // j per LDS stage
#define NST_ (JSPANA_ / JST_)  // 8 stages
#define KCS_ (JST_ / 32)       // 2 MFMA k-steps per stage
#define APAD_ 66               // stores 2-way (free), reads 4-way (1.58x) - LDS not bottleneck

typedef __attribute__((ext_vector_type(8))) short short8v;   // 8 bf16 = 4 VGPRs
typedef __attribute__((ext_vector_type(4))) float f32x4;     // MFMA C/D
typedef __attribute__((ext_vector_type(4))) int   int4v;

union PkU { int4v i; short8v s; };

__device__ __forceinline__ unsigned short f2bf(float f) {    // RNE fp32->bf16
    unsigned u = __float_as_uint(f);
    u += 0x7fffu + ((u >> 16) & 1u);
    return (unsigned short)(u >> 16);
}

// 8 elementwise attn values -> l,A accumulate + packed bf16 A-frag dword x4.
// p >= 0 always; round-half-up (u+0x8000) then hi16 via v_perm pair-pack.
__device__ __forceinline__ void attn_qstep(
    float si, const float* av, const float* mv, const float* tv,
    float& l, float& A, int4v& apk)
{
#pragma unroll
    for (int qq = 0; qq < 4; ++qq) {
        float d0 = si + tv[2 * qq];
        d0 = fmaxf(d0, 0.2f * d0) + mv[2 * qq];       // LeakyReLU(0.2) + mask
        float e0 = __expf(d0);                        // bounded: no max-subtract
        float p0 = e0 * av[2 * qq];
        float d1 = si + tv[2 * qq + 1];
        d1 = fmaxf(d1, 0.2f * d1) + mv[2 * qq + 1];
        float e1 = __expf(d1);
        float p1 = e1 * av[2 * qq + 1];
        l += e0 + e1;
        A += p0 + p1;
        unsigned u0 = __float_as_uint(p0) + 0x8000u;
        unsigned u1 = __float_as_uint(p1) + 0x8000u;
        apk[qq] = (int)__builtin_amdgcn_perm(u1, u0, 0x07060302u); // [p1.hi|p0.hi]
    }
}

// ---------------------------------------------------------------- kernel 1
// feats = x@W per head via MFMA; writes featsT bf16 [b][h][d][n] + s,t fp32.
// Also zero-inits the two loss slots of out (stream order precedes final).
__global__ __launch_bounds__(256) void prep_kernel(
    const float* __restrict__ x, const float* __restrict__ W,
    const float* __restrict__ a_self, const float* __restrict__ a_neigh,
    unsigned short* __restrict__ featsT, float* __restrict__ sbuf,
    float* __restrict__ tbuf, float* __restrict__ out)
{
    int blk = blockIdx.x;              // b*32 + nt
    int b = blk >> 5, nt = blk & 31;
    int n0 = nt << 6;
    int t = threadIdx.x, h = t >> 6, lane = t & 63;
    int quad = lane >> 4, col = lane & 15;
    if (blk == 0 && t == 0) {
        out[(size_t)B_ * N_ * C_]     = 0.f;   // uloss == 0 identically
        out[(size_t)B_ * N_ * C_ + 1] = 0.f;   // eloss accumulated by final
    }

    short8v bw[2][2];
    const float* Wh = W + (size_t)h * F_ * FP_;
#pragma unroll
    for (int kc = 0; kc < 2; ++kc)
#pragma unroll
        for (int dt = 0; dt < 2; ++dt)
#pragma unroll
            for (int e = 0; e < 8; ++e) {
                int f = kc * 32 + quad * 8 + e;
                bw[kc][dt][e] = (short)f2bf(Wh[f * FP_ + dt * 16 + col]);
            }
    float as0 = a_self[h * FP_ + col],  as1 = a_self[h * FP_ + 16 + col];
    float an0 = a_neigh[h * FP_ + col], an1 = a_neigh[h * FP_ + 16 + col];
    size_t hrow = ((size_t)b * H_ + h) * N_;
    size_t ftb  = ((size_t)b * H_ + h) * FP_;

    for (int ms = 0; ms < 4; ++ms) {
        int row = n0 + ms * 16 + col;          // A row m = lane&15
        const float* xr = x + ((size_t)b * N_ + row) * F_;
        f32x4 acc0 = {0.f, 0.f, 0.f, 0.f}, acc1 = {0.f, 0.f, 0.f, 0.f};
#pragma unroll
        for (int kc = 0; kc < 2; ++kc) {
            float4 x0 = *(const float4*)(xr + kc * 32 + quad * 8);
            float4 x1 = *(const float4*)(xr + kc * 32 + quad * 8 + 4);
            short8v av;
            av[0] = (short)f2bf(x0.x); av[1] = (short)f2bf(x0.y);
            av[2] = (short)f2bf(x0.z); av[3] = (short)f2bf(x0.w);
            av[4] = (short)f2bf(x1.x); av[5] = (short)f2bf(x1.y);
            av[6] = (short)f2bf(x1.z); av[7] = (short)f2bf(x1.w);
            acc0 = __builtin_amdgcn_mfma_f32_16x16x32_bf16(av, bw[kc][0], acc0, 0, 0, 0);
            acc1 = __builtin_amdgcn_mfma_f32_16x16x32_bf16(av, bw[kc][1], acc1, 0, 0, 0);
        }
        {   // C layout: row = quad*4+rr, col = lane&15 (verified m89/m91)
            ushort4 v0, v1;
            v0.x = f2bf(acc0[0]); v0.y = f2bf(acc0[1]);
            v0.z = f2bf(acc0[2]); v0.w = f2bf(acc0[3]);
            v1.x = f2bf(acc1[0]); v1.y = f2bf(acc1[1]);
            v1.z = f2bf(acc1[2]); v1.w = f2bf(acc1[3]);
            size_t nidx = (size_t)n0 + ms * 16 + quad * 4;
            *(ushort4*)(featsT + (ftb + col) * N_ + nidx)      = v0;
            *(ushort4*)(featsT + (ftb + 16 + col) * N_ + nidx) = v1;
        }
#pragma unroll
        for (int rr = 0; rr < 4; ++rr) {
            float sv = acc0[rr] * as0 + acc1[rr] * as1;
            float tv = acc0[rr] * an0 + acc1[rr] * an1;
#pragma unroll
            for (int off = 8; off; off >>= 1) {
                sv += __shfl_down(sv, off);
                tv += __shfl_down(tv, off);
            }
            if (col == 0) {
                int n = n0 + ms * 16 + quad * 4 + rr;
                sbuf[hrow + n] = sv;
                tbuf[hrow + n] = tv;
            }
        }
    }
}

// ---------------------------------------------------------------- kernel 2
// Block = (b, 32-row i-tile, jc); 4 waves = 4 heads. Double-buffered LDS,
// ONE barrier per stage. Key ordering vs the vmcnt(0)-before-s_barrier drain:
//   barrier -> issue global loads(st+1) -> compute buf[st] -> LDS-commit(st+1)
// so the loads' latency is covered by ~900 cyc of compute, and they are
// consumed (vmcnt waited) BEFORE the next barrier's drain.
__global__ __launch_bounds__(256, 4) void attn_kernel(
    const float* __restrict__ adj, const float* __restrict__ msk,
    const unsigned short* __restrict__ featsT,
    const float* __restrict__ sbuf, const float* __restrict__ tbuf,
    float* __restrict__ part, float* __restrict__ lpart)
{
    __shared__ float lds_adj[2][IT_ * APAD_];
    __shared__ float lds_msk[2][IT_ * APAD_];
    __shared__ float lds_t[2][H_ * JST_];

    int blk = blockIdx.x;
    int jc = blk & (JCA_ - 1);
    int it = (blk >> 2) & (ITILES_ - 1);
    int b  = blk >> 8;
    int t = threadIdx.x, h = t >> 6, lane = t & 63;
    int quad = lane >> 4, r = lane & 15;
    int i0 = it * IT_;
    int jbase = jc * JSPANA_;

    size_t hrow = ((size_t)b * H_ + h) * N_;
    float si0 = sbuf[hrow + i0 + r];
    float si1 = sbuf[hrow + i0 + 16 + r];
    // B-frag: lane(quad,r) holds featsT[d=r][j = slice + quad*8 + e]
    const unsigned short* ft0 = featsT + (((size_t)b * H_ + h) * FP_ + r) * N_
                                + jbase + quad * 8;
    const unsigned short* ft1 = ft0 + (size_t)16 * N_;

    // staging coords: thread t stages rows srow & srow+16, float4 slot sf4
    int srow = t >> 4, sf4 = (t & 15) * 4;
    const float* adjs = adj + ((size_t)b * N_ + i0 + srow) * N_ + jbase + sf4;
    const float* msks = msk + ((size_t)b * N_ + i0 + srow) * N_ + jbase + sf4;
    int th = t >> 6, tj = t & 63;
    const float* tbs = tbuf + ((size_t)b * H_ + th) * N_ + jbase + tj;

    f32x4 acc00 = {0.f,0.f,0.f,0.f}, acc01 = {0.f,0.f,0.f,0.f};
    f32x4 acc10 = {0.f,0.f,0.f,0.f}, acc11 = {0.f,0.f,0.f,0.f};
    float l0 = 0.f, A0 = 0.f, l1 = 0.f, A1 = 0.f;

    // stage-0 preload + commit to buf 0 (only stage with exposed latency)
    float4 ra0 = *(const float4*)(adjs);
    float4 ra1 = *(const float4*)(adjs + (size_t)16 * N_);
    float4 rm0 = *(const float4*)(msks);
    float4 rm1 = *(const float4*)(msks + (size_t)16 * N_);
    float  rt  = tbs[0];
    *(float4*)&lds_adj[0][srow * APAD_ + sf4]        = ra0;
    *(float4*)&lds_adj[0][(srow + 16) * APAD_ + sf4] = ra1;
    *(float4*)&lds_msk[0][srow * APAD_ + sf4]        = rm0;
    *(float4*)&lds_msk[0][(srow + 16) * APAD_ + sf4] = rm1;
    lds_t[0][th * JST_ + tj] = rt;

#pragma unroll
    for (int st = 0; st < NST_; ++st) {
        int cur = st & 1;
        __syncthreads();                  // buf[cur] complete; drains everything
        if (st + 1 < NST_) {              // issue next loads NOW (covered below)
            int jn = (st + 1) * JST_;
            ra0 = *(const float4*)(adjs + jn);
            ra1 = *(const float4*)(adjs + (size_t)16 * N_ + jn);
            rm0 = *(const float4*)(msks + jn);
            rm1 = *(const float4*)(msks + (size_t)16 * N_ + jn);
            rt  = tbs[jn];
        }
        __builtin_amdgcn_sched_barrier(0);   // keep loads hoisted here
#pragma unroll
        for (int kc = 0; kc < KCS_; ++kc) {
            int jt = kc * 32 + quad * 8;               // col within stage
            int jl = st * JST_ + kc * 32;              // featsT idx (quad*8 in ptr)
            float4 t0 = *(const float4*)&lds_t[cur][h * JST_ + jt];  // broadcast
            float4 t1 = *(const float4*)&lds_t[cur][h * JST_ + jt + 4];
            short8v bv0 = *(const short8v*)(ft0 + jl);
            short8v bv1 = *(const short8v*)(ft1 + jl);
            float tv[8] = {t0.x, t0.y, t0.z, t0.w, t1.x, t1.y, t1.z, t1.w};
            PkU ap0, ap1;
            {   // rows r
                float4 a0 = *(const float4*)&lds_adj[cur][r * APAD_ + jt];
                float4 a1 = *(const float4*)&lds_adj[cur][r * APAD_ + jt + 4];
                float4 m0 = *(const float4*)&lds_msk[cur][r * APAD_ + jt];
                float4 m1 = *(const float4*)&lds_msk[cur][r * APAD_ + jt + 4];
                float av[8] = {a0.x,a0.y,a0.z,a0.w,a1.x,a1.y,a1.z,a1.w};
                float mv[8] = {m0.x,m0.y,m0.z,m0.w,m1.x,m1.y,m1.z,m1.w};
                attn_qstep(si0, av, mv, tv, l0, A0, ap0.i);
            }
            {   // rows r+16
                float4 a0 = *(const float4*)&lds_adj[cur][(r + 16) * APAD_ + jt];
                float4 a1 = *(const float4*)&lds_adj[cur][(r + 16) * APAD_ + jt + 4];
                float4 m0 = *(const float4*)&lds_msk[cur][(r + 16) * APAD_ + jt];
                float4 m1 = *(const float4*)&lds_msk[cur][(r + 16) * APAD_ + jt + 4];
                float av[8] = {a0.x,a0.y,a0.z,a0.w,a1.x,a1.y,a1.z,a1.w};
                float mv[8] = {m0.x,m0.y,m0.z,m0.w,m1.x,m1.y,m1.z,m1.w};
                attn_qstep(si1, av, mv, tv, l1, A1, ap1.i);
            }
            acc00 = __builtin_amdgcn_mfma_f32_16x16x32_bf16(ap0.s, bv0, acc00, 0, 0, 0);
            acc01 = __builtin_amdgcn_mfma_f32_16x16x32_bf16(ap0.s, bv1, acc01, 0, 0, 0);
            acc10 = __builtin_amdgcn_mfma_f32_16x16x32_bf16(ap1.s, bv0, acc10, 0, 0, 0);
            acc11 = __builtin_amdgcn_mfma_f32_16x16x32_bf16(ap1.s, bv1, acc11, 0, 0, 0);
        }
        __builtin_amdgcn_sched_barrier(0);   // commit stays after compute
        if (st + 1 < NST_) {                 // vmcnt wait lands HERE (covered)
            int nxt = (st + 1) & 1;
            *(float4*)&lds_adj[nxt][srow * APAD_ + sf4]        = ra0;
            *(float4*)&lds_adj[nxt][(srow + 16) * APAD_ + sf4] = ra1;
            *(float4*)&lds_msk[nxt][srow * APAD_ + sf4]        = rm0;
            *(float4*)&lds_msk[nxt][(srow + 16) * APAD_ + sf4] = rm1;
            lds_t[nxt][th * JST_ + tj] = rt;
        }
        // no second barrier: buf[nxt]'s previous readers all passed this
        // stage's barrier already (one-barrier double-buffer invariant)
    }
    // fold 4 k-group lanes -> row totals in lanes 0-15
    l0 += __shfl_down(l0, 32); l0 += __shfl_down(l0, 16);
    l1 += __shfl_down(l1, 32); l1 += __shfl_down(l1, 16);
    A0 += __shfl_down(A0, 32); A0 += __shfl_down(A0, 16);
    A1 += __shfl_down(A1, 32); A1 += __shfl_down(A1, 16);

    size_t pb = (((size_t)(b * H_ + h) * ITILES_ + it) * JCA_ + jc) * 1024;
    *(f32x4*)&part[pb + lane * 4]       = acc00;   // raw C-frags, coalesced
    *(f32x4*)&part[pb + 256 + lane * 4] = acc01;
    *(f32x4*)&part[pb + 512 + lane * 4] = acc10;
    *(f32x4*)&part[pb + 768 + lane * 4] = acc11;
    if (lane < 16) {
        size_t lb = (((size_t)(b * H_ + h) * ITILES_ + it) * JCA_ + jc) * 64;
        lpart[lb + lane]      = l0;      // rows 0-15
        lpart[lb + 16 + lane] = l1;      // rows 16-31
        lpart[lb + 32 + lane] = A0;
        lpart[lb + 48 + lane] = A1;
    }
}

// ---------------------------------------------------------------- kernel 3
// Block = (b, 32-row i-tile). Merge jc partials, /l, bias, BN, ReLU,
// LDS transpose, coalesced out; eloss via one atomicAdd per (block,h).
__global__ __launch_bounds__(256) void final_kernel(
    const float* __restrict__ part, const float* __restrict__ lpart,
    const float* __restrict__ bias, const float* __restrict__ gamma,
    const float* __restrict__ beta, const float* __restrict__ mmean,
    const float* __restrict__ mvar, float* __restrict__ out)
{
    __shared__ float ldsl[H_ * IT_];
    __shared__ float ldso[IT_ * 132];
    int blk = blockIdx.x;              // b*64 + it
    int b = blk >> 6, it = blk & 63;
    int t = threadIdx.x, h = t >> 6, lane = t & 63;
    int quad = lane >> 4, col = lane & 15;

    size_t pb = (((size_t)(b * H_ + h) * ITILES_ + it) * JCA_) * 1024;
    f32x4 C[4];
#pragma unroll
    for (int k = 0; k < 4; ++k) C[k] = (f32x4){0.f, 0.f, 0.f, 0.f};
#pragma unroll
    for (int c = 0; c < JCA_; ++c)
#pragma unroll
        for (int k = 0; k < 4; ++k)
            C[k] += *(const f32x4*)&part[pb + c * 1024 + k * 256 + lane * 4];

    size_t lb = (((size_t)(b * H_ + h) * ITILES_ + it) * JCA_) * 64;
    if (lane < 32) {
        float lt = 0.f, At = 0.f;
#pragma unroll
        for (int c = 0; c < JCA_; ++c) {
            lt += lpart[lb + c * 64 + lane];
            At += lpart[lb + c * 64 + 32 + lane];
        }
        ldsl[h * IT_ + lane] = lt;
        float e = At / lt;
#pragma unroll
        for (int off = 16; off; off >>= 1) e += __shfl_down(e, off);
        if (lane == 0)
            atomicAdd(out + (size_t)B_ * N_ * C_ + 1, e * (1.f / N_));
    }
    __syncthreads();
#pragma unroll
    for (int dt = 0; dt < 2; ++dt) {
        int c = h * FP_ + dt * 16 + col;
        float sc = rsqrtf(mvar[c] + 1e-3f) * gamma[c];
        float sh = beta[c] - mmean[c] * sc;
        float bi = bias[c];
#pragma unroll
        for (int rr = 0; rr < 2; ++rr) {
            f32x4 Cv = C[rr * 2 + dt];
#pragma unroll
            for (int rrr = 0; rrr < 4; ++rrr) {
                int row = rr * 16 + quad * 4 + rrr;
                float node = Cv[rrr] / ldsl[h * IT_ + row] + bi;
                float o = node * sc + sh;
                ldso[row * 132 + c] = o > 0.f ? o : 0.f;
            }
        }
    }
    __syncthreads();
#pragma unroll
    for (int ps = 0; ps < 4; ++ps) {
        int s = ps * 256 + t;
        int row = s >> 5, c4 = (s & 31) * 4;
        *(float4*)(out + ((size_t)b * N_ + it * IT_ + row) * C_ + c4) =
            *(const float4*)&ldso[row * 132 + c4];
    }
}

// ---------------------------------------------------------------- launch
extern "C" void kernel_launch(void* const* d_in, const int* in_sizes, int n_in,
                              void* d_out, int out_size, void* d_ws, size_t ws_size,
                              hipStream_t stream)
{
    const float* x         = (const float*)d_in[0];
    const float* adj       = (const float*)d_in[1];
    const float* attn_mask = (const float*)d_in[2];
    const float* W         = (const float*)d_in[3];
    const float* a_self    = (const float*)d_in[4];
    const float* a_neigh   = (const float*)d_in[5];
    const float* bias      = (const float*)d_in[6];
    const float* gamma     = (const float*)d_in[7];
    const float* beta      = (const float*)d_in[8];
    const float* mmean     = (const float*)d_in[9];
    const float* mvar      = (const float*)d_in[10];
    float* out = (float*)d_out;

    float* ws = (float*)d_ws;
    unsigned short* featsT = (unsigned short*)ws;                      // 1,048,576 u16
    float* sbuf  = ws + 524288;                                        //    32,768 f
    float* tbuf  = sbuf + (size_t)B_ * H_ * N_;                        //    32,768 f
    float* part  = tbuf + (size_t)B_ * H_ * N_;                        // 4,194,304 f
    float* lpart = part + (size_t)B_ * H_ * ITILES_ * JCA_ * 1024;     //   262,144 f

    hipLaunchKernelGGL(prep_kernel, dim3(B_ * 32), dim3(256), 0, stream,
                       x, W, a_self, a_neigh, featsT, sbuf, tbuf, out);
    hipLaunchKernelGGL(attn_kernel, dim3(B_ * ITILES_ * JCA_), dim3(256), 0, stream,
                       adj, attn_mask, featsT, sbuf, tbuf, part, lpart);
    hipLaunchKernelGGL(final_kernel, dim3(B_ * ITILES_), dim3(256), 0, stream,
                       part, lpart, bias, gamma, beta, mmean, mvar, out);
}